// Round 10
// baseline (2109.341 us; speedup 1.0000x reference)
//
#include <hip/hip_runtime.h>
#include <hip/hip_fp16.h>

// Unidir_LSTM: h_t = sig(o)*tanh(sig(i)*tanh(g)); f-gate dead (cell carry always 0).
// R14 (resubmit; R9-rule: GPU acquisition timeout = infra, kernel never ran).
//   Smoking gun in VGPR_Count: every version declared "persistent register
//   weights" (R13: 144 regs/thread declared) but reported VGPR=100 (R11: 288 vs
//   180, R0: 192 vs 136) — impossible. The weights are loads from const __restrict__
//   arrays -> LLVM proves them INVARIANT -> REMATERIALIZABLE -> the allocator
//   reloads every fragment from L2 INSIDE EVERY STEP instead of keeping them live.
//   ~36-72 extra VMEM loads (waitcnt-batched, ~300cy) in each step's serial chain =
//   the ~7000 unexplained cycles R12's free-run exposed; explains why all protocol
//   and occupancy changes were null.
// Fix:
//   - Pin weight frags with asm volatile("" : "+v"(frag)) after preload: value
//     becomes opaque -> remat illegal -> stays in registers.
//   - Shape for budget: 512 blocks x 256 thr (8 bg x 64 col-blocks of 16 cols),
//     4 waves = K-quarters; ~230 regs/wave; __launch_bounds__(256,2) caps at 256
//     => guaranteed 2 blocks/CU, all 512 co-resident (no deadlock).
//   - NO memory-clobber asm in the loop: poll->h ordering via data dependency
//     (hp += (v>>8), always 0); store->flag via plain __syncthreads (drains
//     vmcnt(0) before s_barrier) + tid0 agent fetch_add. Hang-proof primitives.
// Predict: VGPR 100 -> ~230-256 (THE signature), recur 1100 -> 400-700us (total
//   ~550-850), MfmaUtil 18-28%, FETCH ~86MB, WRITE ~68MB (jump = spill alarm).
//   If VGPR jumps but time doesn't: next round = s_memtime phase instrumentation.

typedef __fp16 f16x8 __attribute__((ext_vector_type(8)));
typedef __fp16 f16x4 __attribute__((ext_vector_type(4)));
typedef float  f32x4 __attribute__((ext_vector_type(4)));

#define MFMA16(a, b, c) __builtin_amdgcn_mfma_f32_16x16x32_f16(a, b, c, 0, 0, 0)

__device__ __forceinline__ float sigmoid_f(float x) {
  return 1.f / (1.f + __expf(-x));
}
__device__ __forceinline__ float tanh_f(float x) {
  x = fminf(fmaxf(x, -15.f), 15.f);
  float e = __expf(2.f * x);
  return (e - 1.f) / (e + 1.f);
}

static constexpr int SS = 256;

// ---------------- prep: pack W_ih/W_hh rows {i,g,o} to fp16, bias3 = b_ih+b_hh ----
__global__ void prep_kernel(const float* __restrict__ W_ih, const float* __restrict__ W_hh,
                            const float* __restrict__ b_ih, const float* __restrict__ b_hh,
                            __fp16* __restrict__ Wi3, __fp16* __restrict__ Wh3,
                            float* __restrict__ bias3) {
  int j3 = blockIdx.x;                 // 0..3071 packed row
  int g = j3 >> 10, j = j3 & 1023;
  int orig = (g == 0 ? 0 : (g == 1 ? 2048 : 3072)) + j;  // i,g,o rows of 4H
  int tid = threadIdx.x;
  {
    float4 v = *(const float4*)(W_hh + (size_t)orig * 1024 + tid * 4);
    f16x4 o = {(__fp16)v.x, (__fp16)v.y, (__fp16)v.z, (__fp16)v.w};
    *(f16x4*)(Wh3 + (size_t)j3 * 1024 + tid * 4) = o;
  }
  if (tid < 128) {
    float4 v = *(const float4*)(W_ih + (size_t)orig * 512 + tid * 4);
    f16x4 o = {(__fp16)v.x, (__fp16)v.y, (__fp16)v.z, (__fp16)v.w};
    *(f16x4*)(Wi3 + (size_t)j3 * 512 + tid * 4) = o;
  }
  if (tid == 0) bias3[j3] = b_ih[orig] + b_hh[orig];
}

// ---------------- gather: X[t*128+b][e] = fp16(embed[tok[b][t]][e]) ----------------
__global__ void gather_kernel(const int* __restrict__ tok, const float* __restrict__ emb,
                              __fp16* __restrict__ X) {
  int m = blockIdx.x;                  // 0..32767 = t*128 + b
  int t = m >> 7, b = m & 127;
  int tk = tok[b * SS + t];            // inputs is [B][S]
  int e0 = threadIdx.x * 8;
  const float* src = emb + (size_t)tk * 512 + e0;
  float4 v0 = *(const float4*)src;
  float4 v1 = *(const float4*)(src + 4);
  f16x8 o;
  o[0] = (__fp16)v0.x; o[1] = (__fp16)v0.y; o[2] = (__fp16)v0.z; o[3] = (__fp16)v0.w;
  o[4] = (__fp16)v1.x; o[5] = (__fp16)v1.y; o[6] = (__fp16)v1.z; o[7] = (__fp16)v1.w;
  *(f16x8*)(X + (size_t)m * 512 + e0) = o;
}

// ---------------- recurrence: TRUE register-resident weights, 512 blocks ---------
// 512 blocks = (bg 0..7: 16 batch rows, XCD-pinned via bid&7: 64 blocks/XCD,
// 2/CU) x (n 0..63: 16 h-cols each). 4 waves = 4 K-quarters. Per wave, pinned in
// registers for all 256 steps: wh[3][8] (96 VGPR) + wi[3][4] (48 VGPR). Per step:
// 12 X-MFMAs on prefetched xa, prefetch xa(t+1), poll (bg,t) counter (thr 64),
// h A-frags with v-data-dependency (orders them after the poll, no clobber),
// 24 h-MFMAs, publish 12 partials to parity gbuf, barrier, reduce + epilogue
// (1 h-value/thread), __syncthreads (drains stores via its vmcnt(0)), tid0 agent
// fetch_add on (bg,t+1).
__global__ __launch_bounds__(256, 2) void recur_kernel(const __fp16* __restrict__ Wh3,
                                                       const __fp16* __restrict__ Wi3,
                                                       const __fp16* __restrict__ X,
                                                       const float* __restrict__ bias3,
                                                       __fp16* __restrict__ hbuf,
                                                       int* __restrict__ cnt,
                                                       float* __restrict__ out) {
  const int bid = blockIdx.x;
  const int bg = bid & 7, n = bid >> 3;   // bg: XCD-local batch group; n: col-block
  const int b0 = bg * 16, j0 = n * 16;
  const int tid = threadIdx.x, wid = tid >> 6, lane = tid & 63;
  const int l15 = lane & 15, quad = lane >> 4;
  const int kq = wid;                     // this wave's K-quarter

  // parity-double-buffered; row stride 20 floats -> ~2-way banks (free, m136)
  __shared__ float gbuf[2][4][3][16][20];

  // persistent B fragments (col = j0 + l15, k = kq*quarter + kk*32 + quad*8)
  f16x8 wh[3][8];
  f16x8 wi[3][4];
#pragma unroll
  for (int g = 0; g < 3; ++g) {
    const __fp16* wr = Wh3 + (size_t)(g * 1024 + j0 + l15) * 1024 + kq * 256 + quad * 8;
#pragma unroll
    for (int kk = 0; kk < 8; ++kk) wh[g][kk] = *(const f16x8*)(wr + kk * 32);
    const __fp16* wr2 = Wi3 + (size_t)(g * 1024 + j0 + l15) * 512 + kq * 128 + quad * 8;
#pragma unroll
    for (int kk = 0; kk < 4; ++kk) wi[g][kk] = *(const f16x8*)(wr2 + kk * 32);
  }
  // PIN: make the loaded values opaque -> rematerialization (re-load from L2 every
  // step) becomes illegal -> the allocator must keep them register-resident.
#pragma unroll
  for (int g = 0; g < 3; ++g) {
#pragma unroll
    for (int kk = 0; kk < 8; ++kk) asm volatile("" : "+v"(wh[g][kk]));
#pragma unroll
    for (int kk = 0; kk < 4; ++kk) asm volatile("" : "+v"(wi[g][kk]));
  }

  float bs[3];
#pragma unroll
  for (int g = 0; g < 3; ++g) bs[g] = bias3[g * 1024 + j0 + l15];

  const __fp16* xrow = X + (size_t)(b0 + l15) * 512 + kq * 128 + quad * 8;
  const __fp16* hrow = hbuf + (size_t)(b0 + l15) * 1024 + kq * 256 + quad * 8;
  int* cbase = cnt + bg * (SS * 16);      // one 64B line per (bg, t)

  // preload X A-frags for t=0
  f16x8 xa[4];
#pragma unroll
  for (int kk = 0; kk < 4; ++kk) xa[kk] = *(const f16x8*)(xrow + kk * 32);

  for (int t = 0; t < SS; ++t) {
    // (a) X-MFMAs on prefetched frags — h-independent, before the poll
    f32x4 acc[3];
#pragma unroll
    for (int g = 0; g < 3; ++g) {
      f32x4 z = {0.f, 0.f, 0.f, 0.f};
      acc[g] = z;
    }
#pragma unroll
    for (int kk = 0; kk < 4; ++kk)
#pragma unroll
      for (int g = 0; g < 3; ++g)
        acc[g] = MFMA16(xa[kk], wi[g][kk], acc[g]);
    // (a2) prefetch X A-frags for t+1; latency retires under poll + h-phase
    {
      const int tn = (t + 1 < SS) ? t + 1 : t;
      const __fp16* xp = xrow + (size_t)tn * 65536;
#pragma unroll
      for (int kk = 0; kk < 4; ++kk) xa[kk] = *(const f16x8*)(xp + kk * 32);
    }
    // (b) wait for the 64 producer blocks of our batch group (agent relaxed load
    //     of one aggregated counter; R12 measured this costs ~0)
    int v = 64;
    if (t > 0) {
      const int* pollp = cbase + t * 16;
      for (;;) {
        v = __hip_atomic_load(pollp, __ATOMIC_RELAXED, __HIP_MEMORY_SCOPE_AGENT);
        if (v >= 64) break;
        __builtin_amdgcn_s_sleep(1);
      }
    }
    // (c) h A-frags global->VGPR. (v>>8)==0 always, but the data dependency on the
    //     poll result orders these loads after the poll WITHOUT a memory clobber
    //     (clobbers would also force per-step reload of everything).
    f16x8 ha[8];
    {
      const __fp16* hp = hrow + (size_t)t * 131072 + (v >> 8);
#pragma unroll
      for (int kk = 0; kk < 8; ++kk) ha[kk] = *(const f16x8*)(hp + kk * 32);
    }
#pragma unroll
    for (int kk = 0; kk < 8; ++kk)
#pragma unroll
      for (int g = 0; g < 3; ++g)
        acc[g] = MFMA16(ha[kk], wh[g][kk], acc[g]);
    // (d) publish partials to parity gbuf (12 ds_write_b32/thread)
    const int tp = t & 1;
#pragma unroll
    for (int g = 0; g < 3; ++g)
#pragma unroll
      for (int r = 0; r < 4; ++r)
        gbuf[tp][kq][g][quad * 4 + r][l15] = acc[g][r];
    __syncthreads();
    // (e) reduce + epilogue: ONE h-value per thread (256 threads = 16x16 outputs);
    //     wave kq owns row-quad kq: row_i = kq*4 + quad, col = l15.
    {
      const int row_i = kq * 4 + quad;
      float s[3];
#pragma unroll
      for (int g = 0; g < 3; ++g)
        s[g] = gbuf[tp][0][g][row_i][l15] + gbuf[tp][1][g][row_i][l15] +
               gbuf[tp][2][g][row_i][l15] + gbuf[tp][3][g][row_i][l15];
      float gi = s[0] + bs[0];
      float gg = s[1] + bs[1];
      float go = s[2] + bs[2];
      float cv = sigmoid_f(gi) * tanh_f(gg);
      float hN = sigmoid_f(go) * tanh_f(cv);
      const int row = b0 + row_i;
      const int col = j0 + l15;
      if (t == SS - 1) out[(size_t)row * 1024 + col] = hN;
      else hbuf[(size_t)(t + 1) * 131072 + (size_t)row * 1024 + col] = (__fp16)hN;
    }
    // (f) release: __syncthreads drains each wave's stores (its codegen emits
    //     s_waitcnt vmcnt(0) before s_barrier), then ONE agent fetch_add (MALL,
    //     device-visible, hang-proof; R12 measured ~0 cost).
    if (t < SS - 1) {
      __syncthreads();
      if (tid == 0)
        __hip_atomic_fetch_add(cbase + (t + 1) * 16, 1,
                               __ATOMIC_RELAXED, __HIP_MEMORY_SCOPE_AGENT);
    }
  }
}

extern "C" void kernel_launch(void* const* d_in, const int* in_sizes, int n_in,
                              void* d_out, int out_size, void* d_ws, size_t ws_size,
                              hipStream_t stream) {
  const int*   tok  = (const int*)d_in[0];
  const float* emb  = (const float*)d_in[1];
  const float* W_ih = (const float*)d_in[2];
  const float* W_hh = (const float*)d_in[3];
  const float* b_ih = (const float*)d_in[4];
  const float* b_hh = (const float*)d_in[5];
  float* out = (float*)d_out;
  char* ws = (char*)d_ws;

  // ws layout (bytes), total 110,243,840 (~105 MB)
  __fp16* X     = (__fp16*)(ws + 0);              // 33,554,432
  __fp16* Wi3   = (__fp16*)(ws + 33554432);       //  3,145,728
  __fp16* Wh3   = (__fp16*)(ws + 36700160);       //  6,291,456
  float*  bias3 = (float*) (ws + 42991616);       //     12,288
  int*    cnt   = (int*)   (ws + 43003904);       //    131,072 (8 grp x 256 t, 64B lines)
  __fp16* hbuf  = (__fp16*)(ws + 43134976);       // 67,108,864 (256 step buffers)

  (void)hipMemsetAsync(cnt, 0, 131072, stream);
  (void)hipMemsetAsync(hbuf, 0, 131072 * 2, stream);  // h_0 = 0

  prep_kernel<<<3072, 256, 0, stream>>>(W_ih, W_hh, b_ih, b_hh, Wi3, Wh3, bias3);
  gather_kernel<<<32768, 64, 0, stream>>>(tok, emb, X);
  recur_kernel<<<512, 256, 0, stream>>>(Wh3, Wi3, X, bias3, hbuf, cnt, out);
}

// Round 11
// 1409.183 us; speedup vs baseline: 1.4969x; 1.4969x over previous
//
#include <hip/hip_runtime.h>
#include <hip/hip_fp16.h>

// Unidir_LSTM: h_t = sig(o)*tanh(sig(i)*tanh(g)); f-gate dead (cell carry always 0).
// R15: R14 post-mortem: VGPR stayed 100 AND time doubled. gfx950 has a unified
//   VGPR/AGPR file and rocprof VGPR_Count excludes AGPRs — the weights were in
//   AGPRs (MFMA reads B from AGPR natively) ALL ALONG. The asm "+v" pins forced
//   them into arch VGPRs -> scratch spills -> 2x regression. Remat theory dead.
//   R13 (1100us) codegen was already optimal; revert to it EXACTLY.
//   The 3x model-vs-measured gap survives; two independent estimates (MfmaUtil,
//   VALUBusy) both imply effective clock ~725-875 MHz (DVFS parked: latency-bound
//   kernel at 10-20% util never lifts DPM).
// This round: R13-exact recur + pump_kernel before it: 2048x256 pure dependent-FMA
//   with KNOWN cycle count (8 waves/SIMD x 12288 x 2cy = 196,608 cy/SIMD).
//   Probe-by-subtraction: pump_dur = total - recur - ~135us. 82us @2.4GHz vs
//   ~270us @725MHz. Doubles as DVFS warmup immediately before recur.
// Decision rules (committed): recur<900 => DVFS exploitable, next = concurrent
//   pump blocks inside recur grid. recur~1100 & pump~270 => clock platform-capped,
//   pivot to serial-chain structure. recur~1100 & pump~82 => clock load-responsive
//   but recur parks it => concurrent pump next. Signature: clock speedup drops dur
//   at CONSTANT MfmaUtil; structural speedup raises MfmaUtil.

typedef __fp16 f16x8 __attribute__((ext_vector_type(8)));
typedef __fp16 f16x4 __attribute__((ext_vector_type(4)));
typedef float  f32x4 __attribute__((ext_vector_type(4)));

#define MFMA16(a, b, c) __builtin_amdgcn_mfma_f32_16x16x32_f16(a, b, c, 0, 0, 0)

__device__ __forceinline__ float sigmoid_f(float x) {
  return 1.f / (1.f + __expf(-x));
}
__device__ __forceinline__ float tanh_f(float x) {
  x = fminf(fmaxf(x, -15.f), 15.f);
  float e = __expf(2.f * x);
  return (e - 1.f) / (e + 1.f);
}

static constexpr int SS = 256;

// ---------------- pump/probe: known-cycle dependent-FMA, 8 waves/SIMD ------------
// 2048 blocks x 256 thr = 32 waves/CU (needs <=64 VGPR -> launch_bounds(256,8)).
// Per thread: niter*16 dependent FMAs. SIMD issue cycles = 8 waves * 12288 * 2 =
// 196,608 -> 82us @2.4GHz, ~270us @725MHz. Duration recovered by subtraction from
// total. Also serves as DVFS warmup for the recur that follows.
__global__ __launch_bounds__(256, 8) void pump_kernel(int niter, float a, float b,
                                                      float* __restrict__ scratch) {
  float x = (float)threadIdx.x * 1e-6f;
  for (int i = 0; i < niter; ++i) {
#pragma unroll
    for (int u = 0; u < 16; ++u) x = fmaf(x, a, b);
  }
  scratch[(size_t)blockIdx.x * 256 + threadIdx.x] = x;  // keep the chain live
}

// ---------------- prep: pack W_ih/W_hh rows {i,g,o} to fp16, bias3 = b_ih+b_hh ----
__global__ void prep_kernel(const float* __restrict__ W_ih, const float* __restrict__ W_hh,
                            const float* __restrict__ b_ih, const float* __restrict__ b_hh,
                            __fp16* __restrict__ Wi3, __fp16* __restrict__ Wh3,
                            float* __restrict__ bias3) {
  int j3 = blockIdx.x;                 // 0..3071 packed row
  int g = j3 >> 10, j = j3 & 1023;
  int orig = (g == 0 ? 0 : (g == 1 ? 2048 : 3072)) + j;  // i,g,o rows of 4H
  int tid = threadIdx.x;
  {
    float4 v = *(const float4*)(W_hh + (size_t)orig * 1024 + tid * 4);
    f16x4 o = {(__fp16)v.x, (__fp16)v.y, (__fp16)v.z, (__fp16)v.w};
    *(f16x4*)(Wh3 + (size_t)j3 * 1024 + tid * 4) = o;
  }
  if (tid < 128) {
    float4 v = *(const float4*)(W_ih + (size_t)orig * 512 + tid * 4);
    f16x4 o = {(__fp16)v.x, (__fp16)v.y, (__fp16)v.z, (__fp16)v.w};
    *(f16x4*)(Wi3 + (size_t)j3 * 512 + tid * 4) = o;
  }
  if (tid == 0) bias3[j3] = b_ih[orig] + b_hh[orig];
}

// ---------------- gather: X[t*128+b][e] = fp16(embed[tok[b][t]][e]) ----------------
__global__ void gather_kernel(const int* __restrict__ tok, const float* __restrict__ emb,
                              __fp16* __restrict__ X) {
  int m = blockIdx.x;                  // 0..32767 = t*128 + b
  int t = m >> 7, b = m & 127;
  int tk = tok[b * SS + t];            // inputs is [B][S]
  int e0 = threadIdx.x * 8;
  const float* src = emb + (size_t)tk * 512 + e0;
  float4 v0 = *(const float4*)src;
  float4 v1 = *(const float4*)(src + 4);
  f16x8 o;
  o[0] = (__fp16)v0.x; o[1] = (__fp16)v0.y; o[2] = (__fp16)v0.z; o[3] = (__fp16)v0.w;
  o[4] = (__fp16)v1.x; o[5] = (__fp16)v1.y; o[6] = (__fp16)v1.z; o[7] = (__fp16)v1.w;
  *(f16x8*)(X + (size_t)m * 512 + e0) = o;
}

// ---------------- recurrence: R13-EXACT (proven 1100us) ---------------------------
// 256 blocks = (bg 0..7: 16 batch rows, XCD-pinned via bid&7) x (n 0..31: 32
// h-cols). 8 waves = (ct 0..1: 16-col tile) x (kq 0..3: K-quarter). Per step,
// per wave: 12 X-MFMAs on prefetched xa (pre-poll), prefetch xa(t+1), poll the
// single (bg,t) agent counter, 8 h A-frag loads (XCD-L2), 24 h-MFMAs, publish
// 12 partials to parity gbuf, barrier, epilogue 1 h-value/thread, per-wave
// vmcnt(0), release barrier, tid0 agent fetch_add on (bg,t+1).
__global__ __launch_bounds__(512, 2) void recur_kernel(const __fp16* __restrict__ Wh3,
                                                       const __fp16* __restrict__ Wi3,
                                                       const __fp16* __restrict__ X,
                                                       const float* __restrict__ bias3,
                                                       __fp16* __restrict__ hbuf,
                                                       int* __restrict__ cnt,
                                                       float* __restrict__ out) {
  const int bid = blockIdx.x;
  const int bg = bid & 7, n = bid >> 3;   // XCD-local batch groups
  const int b0 = bg * 16, j0 = n * 32;
  const int tid = threadIdx.x, wid = tid >> 6, lane = tid & 63;
  const int l15 = lane & 15, quad = lane >> 4;
  const int kq = wid >> 1, ct = wid & 1;  // compute ownership: K-quarter, col-tile
  const int ct_e = wid & 1, rq = wid >> 1;  // epilogue ownership: col-tile, row-quad
  const int lr = lane >> 4;               // epilogue row within quad (0..3)

  // parity-double-buffered; stride 20 floats -> <=2-way banks (free, m136)
  __shared__ float gbuf[2][4][3][2][16][20];

  // persistent B fragments (col = j0 + ct*16 + l15, k = kq*quarter + kk*32 + quad*8)
  f16x8 wh[3][8];
  f16x8 wi[3][4];
#pragma unroll
  for (int g = 0; g < 3; ++g) {
    const __fp16* wr = Wh3 + (size_t)(g * 1024 + j0 + ct * 16 + l15) * 1024 + kq * 256 + quad * 8;
#pragma unroll
    for (int kk = 0; kk < 8; ++kk) wh[g][kk] = *(const f16x8*)(wr + kk * 32);
    const __fp16* wr2 = Wi3 + (size_t)(g * 1024 + j0 + ct * 16 + l15) * 512 + kq * 128 + quad * 8;
#pragma unroll
    for (int kk = 0; kk < 4; ++kk) wi[g][kk] = *(const f16x8*)(wr2 + kk * 32);
  }

  float bs[3];
#pragma unroll
  for (int g = 0; g < 3; ++g) bs[g] = bias3[g * 1024 + j0 + ct_e * 16 + l15];

  const __fp16* xrow = X + (size_t)(b0 + l15) * 512 + kq * 128 + quad * 8;
  const __fp16* hrow = hbuf + (size_t)(b0 + l15) * 1024 + kq * 256 + quad * 8;
  int* cbase = cnt + bg * (SS * 16);      // one 64B line per (bg, t)

  // preload X A-frags for t=0 (prefetch pipeline prologue)
  f16x8 xa[4];
#pragma unroll
  for (int kk = 0; kk < 4; ++kk) xa[kk] = *(const f16x8*)(xrow + kk * 32);

  for (int t = 0; t < SS; ++t) {
    // (a) X-MFMAs on the prefetched frags — h-independent, before the poll
    f32x4 acc[3];
#pragma unroll
    for (int g = 0; g < 3; ++g) {
      f32x4 z = {0.f, 0.f, 0.f, 0.f};
      acc[g] = z;
    }
#pragma unroll
    for (int kk = 0; kk < 4; ++kk)
#pragma unroll
      for (int g = 0; g < 3; ++g)
        acc[g] = MFMA16(xa[kk], wi[g][kk], acc[g]);
    // (a2) prefetch X A-frags for t+1; latency retires under poll + h-phase
    {
      const int tn = (t + 1 < SS) ? t + 1 : t;
      const __fp16* xp = xrow + (size_t)tn * 65536;
#pragma unroll
      for (int kk = 0; kk < 4; ++kk) xa[kk] = *(const f16x8*)(xp + kk * 32);
    }
    // (b) wait for the 32 producer blocks of our batch group (R9-proven scheme:
    //     agent-scope relaxed load of one aggregated counter; R12 measured ~0 cost)
    if (t > 0) {
      const int* pollp = cbase + t * 16;
      for (;;) {
        int v = __hip_atomic_load(pollp, __ATOMIC_RELAXED, __HIP_MEMORY_SCOPE_AGENT);
        if (v >= 32) break;
        __builtin_amdgcn_s_sleep(1);
      }
      asm volatile("" ::: "memory");
    }
    // (c) h A-frags global->VGPR (XCD-L2 hit), then 24 h-MFMAs
    f16x8 ha[8];
    {
      const __fp16* hp = hrow + (size_t)t * 131072;
#pragma unroll
      for (int kk = 0; kk < 8; ++kk) ha[kk] = *(const f16x8*)(hp + kk * 32);
    }
#pragma unroll
    for (int kk = 0; kk < 8; ++kk)
#pragma unroll
      for (int g = 0; g < 3; ++g)
        acc[g] = MFMA16(ha[kk], wh[g][kk], acc[g]);
    // (d) publish partials to parity gbuf (12 ds_write_b32/thread)
    const int tp = t & 1;
#pragma unroll
    for (int g = 0; g < 3; ++g)
#pragma unroll
      for (int r = 0; r < 4; ++r)
        gbuf[tp][kq][g][ct][quad * 4 + r][l15] = acc[g][r];
    __syncthreads();
    // (e) reduce + epilogue: ONE h-value per thread (512 threads = 16x32 outputs)
    {
      const int row_i = rq * 4 + lr;
      float s[3];
#pragma unroll
      for (int g = 0; g < 3; ++g)
        s[g] = gbuf[tp][0][g][ct_e][row_i][l15] + gbuf[tp][1][g][ct_e][row_i][l15] +
               gbuf[tp][2][g][ct_e][row_i][l15] + gbuf[tp][3][g][ct_e][row_i][l15];
      float gi = s[0] + bs[0];
      float gg = s[1] + bs[1];
      float go = s[2] + bs[2];
      float cv = sigmoid_f(gi) * tanh_f(gg);
      float hN = sigmoid_f(go) * tanh_f(cv);
      const int row = b0 + row_i;
      const int col = j0 + ct_e * 16 + l15;
      if (t == SS - 1) out[(size_t)row * 1024 + col] = hN;
      else hbuf[(size_t)(t + 1) * 131072 + (size_t)row * 1024 + col] = (__fp16)hN;
    }
    // (f) release: per-wave drain into the XCD L2, block barrier, then ONE agent
    //     fetch_add (MALL, device-visible, hang-proof; R12 measured ~0 cost).
    if (t < SS - 1) {
      asm volatile("s_waitcnt vmcnt(0)" ::: "memory");
      __syncthreads();
      if (tid == 0)
        __hip_atomic_fetch_add(cbase + (t + 1) * 16, 1,
                               __ATOMIC_RELAXED, __HIP_MEMORY_SCOPE_AGENT);
    }
  }
}

extern "C" void kernel_launch(void* const* d_in, const int* in_sizes, int n_in,
                              void* d_out, int out_size, void* d_ws, size_t ws_size,
                              hipStream_t stream) {
  const int*   tok  = (const int*)d_in[0];
  const float* emb  = (const float*)d_in[1];
  const float* W_ih = (const float*)d_in[2];
  const float* W_hh = (const float*)d_in[3];
  const float* b_ih = (const float*)d_in[4];
  const float* b_hh = (const float*)d_in[5];
  float* out = (float*)d_out;
  char* ws = (char*)d_ws;

  // ws layout (bytes), total 112,340,992 (~107 MB)
  __fp16* X      = (__fp16*)(ws + 0);              // 33,554,432
  __fp16* Wi3    = (__fp16*)(ws + 33554432);       //  3,145,728
  __fp16* Wh3    = (__fp16*)(ws + 36700160);       //  6,291,456
  float*  bias3  = (float*) (ws + 42991616);       //     12,288
  int*    cnt    = (int*)   (ws + 43003904);       //    131,072 (8 grp x 256 t, 64B lines)
  __fp16* hbuf   = (__fp16*)(ws + 43134976);       // 67,108,864 (256 step buffers)
  float*  pumpws = (float*) (ws + 110243840);      //  2,097,152 (pump sink)

  (void)hipMemsetAsync(cnt, 0, 131072, stream);
  (void)hipMemsetAsync(hbuf, 0, 131072 * 2, stream);  // h_0 = 0

  prep_kernel<<<3072, 256, 0, stream>>>(W_ih, W_hh, b_ih, b_hh, Wi3, Wh3, bias3);
  gather_kernel<<<32768, 64, 0, stream>>>(tok, emb, X);
  // clock probe + DVFS warmup: 196,608 issue-cycles/SIMD => 82us @2.4GHz,
  // ~270us @725MHz. Duration recovered as total - recur - ~135us.
  pump_kernel<<<2048, 256, 0, stream>>>(768, 0.999999f, 1e-6f, pumpws);
  recur_kernel<<<256, 512, 0, stream>>>(Wh3, Wi3, X, bias3, hbuf, cnt, out);
}